// Round 8
// baseline (2264.672 us; speedup 1.0000x reference)
//
#include <hip/hip_runtime.h>
#include <cfloat>

#define NRW 32768
#define KC 4096
#define CD 256
#define HW 1024

// ---------- transpose x (B,C,H,W) -> xT[row][ch], row = b*1024+hw ----------
__global__ __launch_bounds__(256) void vq_xt(const float* __restrict__ x,
                                             float* __restrict__ xT) {
  const int t   = threadIdx.x;                 // channel
  const int b   = blockIdx.x >> 4;
  const int hw0 = (blockIdx.x & 15) << 6;
  const float* src = x + ((size_t)b * CD + t) * HW + hw0;
  float* dst = xT + ((size_t)b * HW + hw0) * CD + t;
#pragma unroll
  for (int f = 0; f < 16; ++f) {
    const float4 v = *(const float4*)(src + 4 * f);
    dst[(size_t)(4 * f + 0) * CD] = v.x;       // coalesced across t
    dst[(size_t)(4 * f + 1) * CD] = v.y;
    dst[(size_t)(4 * f + 2) * CD] = v.z;
    dst[(size_t)(4 * f + 3) * CD] = v.w;
  }
}

// ---------- rowsq[r] = np.sum(row**2): numpy pairwise (128+128, scalar 8-acc) ----------
__global__ __launch_bounds__(256) void vq_rowsq(const float* __restrict__ src,
                                                float* __restrict__ dst) {
#pragma clang fp contract(off)
  const int tid = threadIdx.x;
  const int g = tid >> 3;
  const int j = tid & 7;
  const int row = blockIdx.x * 32 + g;
  const float* e = src + (size_t)row * CD;
  float half[2];
#pragma unroll
  for (int h = 0; h < 2; ++h) {
    const float* a = e + h * 128;
    float v = a[j];
    float r = v * v;
#pragma unroll
    for (int i = 1; i < 16; ++i) {
      float w = a[8 * i + j];
      float w2 = w * w;
      r = r + w2;
    }
    float l1 = r + __shfl_down(r, 1, 8);
    float l2 = l1 + __shfl_down(l1, 2, 8);
    float l3 = l2 + __shfl_down(l2, 4, 8);
    half[h] = l3;
  }
  if (j == 0) dst[row] = half[0] + half[1];
}

// ---------- main: lane=code, wave=8 rows; x via uniform s_load, e via LDS b32 ----------
__global__ __launch_bounds__(256) void vq_dist(const float* __restrict__ xT,
                                               const float* __restrict__ cb,
                                               const float* __restrict__ se,
                                               const float* __restrict__ sx,
                                               float* __restrict__ outids) {
#pragma clang fp contract(off)
  __shared__ float es[3 * 1024];   // 12 KB: 3 buffers of [16ch][64codes]

  const int tid  = threadIdx.x;
  const int lane = tid & 63;
  const int wid  = __builtin_amdgcn_readfirstlane(tid >> 6);
  const int rb   = blockIdx.x * 32 + wid * 8;    // wave's first row (uniform)

  const float* xw  = xT + (size_t)rb * CD;       // uniform base
  const float* sxu = sx + rb;
  float sxr[8];
#pragma unroll
  for (int r = 0; r < 8; ++r) sxr[r] = sxu[r];   // uniform -> SGPR

  // staging map: thread -> (code, 4-channel group) of current chunk
  const int scode = tid & 63;
  const int sch   = (tid >> 6) << 2;             // 0,4,8,12

  // prologue: chunk 0 -> buf0; chunk 1 -> regs
  {
    const float4 v0 = *(const float4*)(cb + (size_t)scode * CD + sch);
    float* d = es + sch * 64 + scode;
    d[0] = v0.x; d[64] = v0.y; d[128] = v0.z; d[192] = v0.w;
  }
  float4 vn = *(const float4*)(cb + (size_t)scode * CD + 16 + sch);
  __syncthreads();

  float acc[8][4];
  float m1[8];
  int   mi[8];
#pragma unroll
  for (int r = 0; r < 8; ++r) {
    m1[r] = FLT_MAX; mi[r] = 0;
    acc[r][0] = 0.f; acc[r][1] = 0.f; acc[r][2] = 0.f; acc[r][3] = 0.f;
  }

  int cur = 0, q = 0;
#pragma unroll 1
  for (int cg = 0; cg < 64; ++cg) {
    const float sev = se[cg * 64 + lane];        // per-lane, coalesced
#pragma unroll 1
    for (int ck = 0; ck < 16; ++ck, ++q) {
      int nxt = cur + 1; if (nxt == 3) nxt = 0;
      if (q < 1023) {                            // publish chunk q+1
        float* d = es + nxt * 1024 + sch * 64 + scode;
        d[0] = vn.x; d[64] = vn.y; d[128] = vn.z; d[192] = vn.w;
      }
      if (q < 1022) {                            // prefetch chunk q+2
        const int q2 = q + 2;
        vn = *(const float4*)(cb + (size_t)((q2 >> 4) * 64 + scode) * CD + (q2 & 15) * 16 + sch);
      }
      // own code's 16 e-values: stride-64 b32, bank = lane%32 (2-way, free)
      const float* eb = es + cur * 1024 + lane;
      float ev[16];
#pragma unroll
      for (int c = 0; c < 16; ++c) ev[c] = eb[c * 64];
      // MACs: rows 0..7 (uniform x via s_load), j=3..0, SSE lane = c mod 4
      const float* xc = xw + ck * 16;
#pragma unroll
      for (int r = 0; r < 8; ++r) {
        const float* xr = xc + r * CD;
#pragma unroll
        for (int j = 3; j >= 0; --j) {
          const float4 xv = *(const float4*)(xr + 4 * j);
          float p0 = xv.x * ev[4 * j + 0]; acc[r][0] = acc[r][0] + p0;
          float p1 = xv.y * ev[4 * j + 1]; acc[r][1] = acc[r][1] + p1;
          float p2 = xv.z * ev[4 * j + 2]; acc[r][2] = acc[r][2] + p2;
          float p3 = xv.w * ev[4 * j + 3]; acc[r][3] = acc[r][3] + p3;
        }
      }
      __syncthreads();
      cur = nxt;
    }
    // finish this cg's 64 codes: SSE tree, sq=(se+sx), dist=sq-2dot, first-min
#pragma unroll
    for (int r = 0; r < 8; ++r) {
      const float dot  = (acc[r][0] + acc[r][1]) + (acc[r][2] + acc[r][3]);
      const float dist = (sev + sxr[r]) - 2.0f * dot;
      const int   k    = cg * 64 + lane;
      if (dist < m1[r]) { m1[r] = dist; mi[r] = k; }   // cg ascends -> first-min
      acc[r][0] = 0.f; acc[r][1] = 0.f; acc[r][2] = 0.f; acc[r][3] = 0.f;
    }
  }

  // cross-lane argmin per row: lexicographic (dist, idx) -> first-index exact
#pragma unroll
  for (int r = 0; r < 8; ++r) {
    float v = m1[r];
    int   idx = mi[r];
#pragma unroll
    for (int off = 32; off > 0; off >>= 1) {
      const float ov = __shfl_xor(v, off, 64);
      const int   oi = __shfl_xor(idx, off, 64);
      if (ov < v || (ov == v && oi < idx)) { v = ov; idx = oi; }
    }
    if (lane == 0) outids[rb + r] = (float)idx;
  }
}

// ---------- emb gather ----------
__global__ __launch_bounds__(256) void vq_emb_out(const float* __restrict__ outids,
                                                  const float* __restrict__ cb,
                                                  float* __restrict__ out) {
  const int bx = blockIdx.x;
  const int b = bx >> 10;
  const int rem = bx & 1023;
  const int c = rem >> 2;
  const int q = rem & 3;
  const int hw = q * 256 + threadIdx.x;
  const int id = (int)outids[b * HW + hw];
  out[((size_t)(b * CD + c)) * HW + hw] = cb[(size_t)id * CD + c];
}

extern "C" void kernel_launch(void* const* d_in, const int* in_sizes, int n_in,
                              void* d_out, int out_size, void* d_ws, size_t ws_size,
                              hipStream_t stream) {
  const float* x  = (const float*)d_in[0];   // (32,256,32,32) f32
  const float* cb = (const float*)d_in[1];   // (4096,256) f32
  float* out = (float*)d_out;                // [0..32767]=ids, [32768..]=emb

  float* se = (float*)d_ws;                  // 16 KB
  float* sx = se + KC;                       // 128 KB
  float* xT = out + NRW;                     // 32 MB scratch = emb region (overwritten last)

  vq_xt<<<512, 256, 0, stream>>>(x, xT);
  vq_rowsq<<<KC / 32, 256, 0, stream>>>(cb, se);
  vq_rowsq<<<NRW / 32, 256, 0, stream>>>(xT, sx);
  vq_dist<<<1024, 256, 0, stream>>>(xT, cb, se, sx, out);
  vq_emb_out<<<32768, 256, 0, stream>>>(out, cb, out + NRW);
}

// Round 9
// 1897.070 us; speedup vs baseline: 1.1938x; 1.1938x over previous
//
#include <hip/hip_runtime.h>
#include <cfloat>

#define NRW 32768
#define KC 4096
#define CD 256
#define HW 1024

// exact numpy fp32 MAC: scalar x times float4-over-codes e; mul & add separately rounded
#define MACS(accv, xsc, ev) do { \
  float p0 = (xsc) * (ev).x; (accv).x = (accv).x + p0; \
  float p1 = (xsc) * (ev).y; (accv).y = (accv).y + p1; \
  float p2 = (xsc) * (ev).z; (accv).z = (accv).z + p2; \
  float p3 = (xsc) * (ev).w; (accv).w = (accv).w + p3; } while (0)

// ---------- se[k] = np.sum(cb[k]**2) : numpy pairwise (128+128, scalar 8-acc) ----------
__global__ __launch_bounds__(256) void vq_se(const float* __restrict__ cb,
                                             float* __restrict__ se) {
#pragma clang fp contract(off)
  const int tid = threadIdx.x;
  const int g = tid >> 3;
  const int j = tid & 7;
  const int code = blockIdx.x * 32 + g;
  const float* e = cb + (size_t)code * CD;
  float half[2];
#pragma unroll
  for (int h = 0; h < 2; ++h) {
    const float* a = e + h * 128;
    float v = a[j];
    float r = v * v;
#pragma unroll
    for (int i = 1; i < 16; ++i) {
      float w = a[8 * i + j];
      float w2 = w * w;
      r = r + w2;
    }
    float l1 = r + __shfl_down(r, 1, 8);
    float l2 = l1 + __shfl_down(l1, 2, 8);
    float l3 = l2 + __shfl_down(l2, 4, 8);
    half[h] = l3;
  }
  if (j == 0) se[code] = half[0] + half[1];
}

// swizzled x LDS address: granule XOR by (row>>3)&3 spreads the 4 wave-distinct rows
__device__ __forceinline__ int xaddr(int row, int ch) {
  return row * 256 + ((((ch >> 2) ^ ((row >> 3) & 3)) << 2) | (ch & 3));
}

// ---------- main: 32 rows in LDS; wave-private double-buffered e; NO barriers in loop ----------
__global__ __launch_bounds__(256) void vq_dist(const float* __restrict__ x,
                                               const float* __restrict__ cb,
                                               const float* __restrict__ se,
                                               float* __restrict__ outids) {
#pragma clang fp contract(off)
  __shared__ float xs[32 * 256];        // 32 KB, swizzled [row][ch]
  __shared__ float ebuf[4 * 2 * 1024];  // 32 KB: 4 waves x 2 bufs x [16ch][64codes]
  __shared__ float sxs[32];
  __shared__ float mval[4 * 32];
  __shared__ int   midx[4 * 32];

  const int tid  = threadIdx.x;
  const int lane = tid & 63;
  const int wid  = tid >> 6;
  const int tx   = lane & 15;           // code quad within chunk
  const int ty   = lane >> 4;           // row group: rows 8ty..8ty+7
  const int b    = blockIdx.x >> 5;
  const int hw0  = (blockIdx.x & 31) << 5;
  const float* xb = x + (size_t)b * CD * HW + hw0;
  const int kwbase = wid << 10;         // wave's 1024-code range

  // ---- stage x once: thread = channel, 8 float4 over 32 rows ----
  {
    const float* src = xb + (size_t)tid * HW;
#pragma unroll
    for (int f = 0; f < 8; ++f) {
      const float4 v = *(const float4*)(src + 4 * f);
      xs[xaddr(4 * f + 0, tid)] = v.x;
      xs[xaddr(4 * f + 1, tid)] = v.y;
      xs[xaddr(4 * f + 2, tid)] = v.z;
      xs[xaddr(4 * f + 3, tid)] = v.w;
    }
  }
  __syncthreads();

  // ---- sx per row: numpy pairwise (128+128, scalar 8-acc), serial per thread ----
  if (tid < 32) {
    const int row = tid;
    float half[2];
#pragma unroll
    for (int h = 0; h < 2; ++h) {
      float racc[8];
#pragma unroll
      for (int j = 0; j < 8; ++j) {
        const float v = xs[xaddr(row, h * 128 + j)];
        racc[j] = v * v;
      }
#pragma unroll
      for (int i = 1; i < 16; ++i) {
#pragma unroll
        for (int j = 0; j < 8; ++j) {
          const float v = xs[xaddr(row, h * 128 + 8 * i + j)];
          const float v2 = v * v;
          racc[j] = racc[j] + v2;
        }
      }
      half[h] = ((racc[0] + racc[1]) + (racc[2] + racc[3])) +
                ((racc[4] + racc[5]) + (racc[6] + racc[7]));
    }
    sxs[row] = half[0] + half[1];
  }
  __syncthreads();

  float sxr[8];
#pragma unroll
  for (int r = 0; r < 8; ++r) sxr[r] = sxs[8 * ty + r];

  float* ebw = ebuf + wid * 2048;       // wave-private: 2 bufs x 1024 floats

  // ---- prologue: chunk 0 -> buf0; chunk 1 -> regs ----
  float4 st[4];
  {
    const float* src = cb + (size_t)(kwbase + lane) * CD;
#pragma unroll
    for (int m = 0; m < 4; ++m) st[m] = *(const float4*)(src + 4 * m);
    float* d = ebw + lane;              // buf0
    d[0]  = st[0].x; d[64]  = st[0].y; d[128] = st[0].z; d[192] = st[0].w;
    d[256] = st[1].x; d[320] = st[1].y; d[384] = st[1].z; d[448] = st[1].w;
    d[512] = st[2].x; d[576] = st[2].y; d[640] = st[2].z; d[704] = st[2].w;
    d[768] = st[3].x; d[832] = st[3].y; d[896] = st[3].z; d[960] = st[3].w;
#pragma unroll
    for (int m = 0; m < 4; ++m) st[m] = *(const float4*)(src + 16 + 4 * m);
  }

  float4 acc[8][4];                     // [row][SSE lane], float4 over 4 codes
  float m1[8];
  int   mi[8];
#pragma unroll
  for (int r = 0; r < 8; ++r) {
    m1[r] = FLT_MAX; mi[r] = 0;
#pragma unroll
    for (int l = 0; l < 4; ++l) { acc[r][l].x = 0.f; acc[r][l].y = 0.f; acc[r][l].z = 0.f; acc[r][l].w = 0.f; }
  }

#pragma unroll 1
  for (int cg = 0; cg < 16; ++cg) {
#pragma unroll 1
    for (int ck = 0; ck < 16; ++ck) {
      const int q = cg * 16 + ck;
      // (1) publish chunk q+1 (regs loaded last chunk) into the other buffer
      if (q < 255) {
        float* d = ebw + ((q + 1) & 1) * 1024 + lane;
        d[0]  = st[0].x; d[64]  = st[0].y; d[128] = st[0].z; d[192] = st[0].w;
        d[256] = st[1].x; d[320] = st[1].y; d[384] = st[1].z; d[448] = st[1].w;
        d[512] = st[2].x; d[576] = st[2].y; d[640] = st[2].z; d[704] = st[2].w;
        d[768] = st[3].x; d[832] = st[3].y; d[896] = st[3].z; d[960] = st[3].w;
      }
      // (2) issue global loads for chunk q+2
      if (q < 254) {
        const int q2 = q + 2;
        const float* src = cb + (size_t)(kwbase + (q2 >> 4) * 64 + lane) * CD + (q2 & 15) * 16;
#pragma unroll
        for (int m = 0; m < 4; ++m) st[m] = *(const float4*)(src + 4 * m);
      }
      // (3) compute chunk q: numpy order (ck blocks ascending, j = 3..0)
      const float* eb = ebw + (q & 1) * 1024 + 4 * tx;
      const float* xck = xs + 16 * ck;
#pragma unroll
      for (int j = 3; j >= 0; --j) {
        float4 ev[4];
#pragma unroll
        for (int l = 0; l < 4; ++l)
          ev[l] = *(const float4*)(eb + (4 * j + l) * 64);
        float4 xv[8];
#pragma unroll
        for (int r = 0; r < 8; ++r)
          xv[r] = *(const float4*)(xck + (8 * ty + r) * 256 + 4 * (j ^ ty));
#pragma unroll
        for (int r = 0; r < 8; ++r) {
          MACS(acc[r][0], xv[r].x, ev[0]);
          MACS(acc[r][1], xv[r].y, ev[1]);
          MACS(acc[r][2], xv[r].z, ev[2]);
          MACS(acc[r][3], xv[r].w, ev[3]);
        }
      }
    }
    // epilogue: SSE tree over l, sq = se+sx, dist = sq - 2*dot, running first-min
    const int kb = kwbase + cg * 64 + 4 * tx;
    const float4 se4 = *(const float4*)(se + kb);
#pragma unroll
    for (int r = 0; r < 8; ++r) {
      float4 dotv;
      dotv.x = (acc[r][0].x + acc[r][1].x) + (acc[r][2].x + acc[r][3].x);
      dotv.y = (acc[r][0].y + acc[r][1].y) + (acc[r][2].y + acc[r][3].y);
      dotv.z = (acc[r][0].z + acc[r][1].z) + (acc[r][2].z + acc[r][3].z);
      dotv.w = (acc[r][0].w + acc[r][1].w) + (acc[r][2].w + acc[r][3].w);
      const float d0 = (se4.x + sxr[r]) - 2.0f * dotv.x;
      const float d1 = (se4.y + sxr[r]) - 2.0f * dotv.y;
      const float d2 = (se4.z + sxr[r]) - 2.0f * dotv.z;
      const float d3 = (se4.w + sxr[r]) - 2.0f * dotv.w;
      if (d0 < m1[r]) { m1[r] = d0; mi[r] = kb; }
      if (d1 < m1[r]) { m1[r] = d1; mi[r] = kb + 1; }
      if (d2 < m1[r]) { m1[r] = d2; mi[r] = kb + 2; }
      if (d3 < m1[r]) { m1[r] = d3; mi[r] = kb + 3; }
#pragma unroll
      for (int l = 0; l < 4; ++l) { acc[r][l].x = 0.f; acc[r][l].y = 0.f; acc[r][l].z = 0.f; acc[r][l].w = 0.f; }
    }
  }

  // ---- merge: 16 lanes (same ty) per row, lexicographic; then 4 waves via LDS ----
#pragma unroll
  for (int r = 0; r < 8; ++r) {
    float v = m1[r];
    int   idx = mi[r];
#pragma unroll
    for (int off = 1; off < 16; off <<= 1) {
      const float ov = __shfl_xor(v, off, 16);
      const int   oi = __shfl_xor(idx, off, 16);
      if (ov < v || (ov == v && oi < idx)) { v = ov; idx = oi; }
    }
    if (tx == 0) {
      mval[wid * 32 + 8 * ty + r] = v;
      midx[wid * 32 + 8 * ty + r] = idx;
    }
  }
  __syncthreads();
  if (tid < 32) {
    float best = mval[tid];
    int   bi   = midx[tid];
#pragma unroll
    for (int ww = 1; ww < 4; ++ww) {
      const float v  = mval[ww * 32 + tid];
      const int   ix = midx[ww * 32 + tid];
      if (v < best || (v == best && ix < bi)) { best = v; bi = ix; }
    }
    outids[b * HW + hw0 + tid] = (float)bi;
  }
}

// ---------- emb gather ----------
__global__ __launch_bounds__(256) void vq_emb_out(const float* __restrict__ outids,
                                                  const float* __restrict__ cb,
                                                  float* __restrict__ out) {
  const int bx = blockIdx.x;
  const int b = bx >> 10;
  const int rem = bx & 1023;
  const int c = rem >> 2;
  const int q = rem & 3;
  const int hw = q * 256 + threadIdx.x;
  const int id = (int)outids[b * HW + hw];
  out[((size_t)(b * CD + c)) * HW + hw] = cb[(size_t)id * CD + c];
}

extern "C" void kernel_launch(void* const* d_in, const int* in_sizes, int n_in,
                              void* d_out, int out_size, void* d_ws, size_t ws_size,
                              hipStream_t stream) {
  const float* x  = (const float*)d_in[0];   // (32,256,32,32) f32
  const float* cb = (const float*)d_in[1];   // (4096,256) f32
  float* out = (float*)d_out;                // [0..32767]=ids, [32768..]=emb

  float* se = (float*)d_ws;                  // 16 KB

  vq_se<<<KC / 32, 256, 0, stream>>>(cb, se);
  vq_dist<<<NRW / 32, 256, 0, stream>>>(x, cb, se, out);
  vq_emb_out<<<32768, 256, 0, stream>>>(out, cb, out + NRW);
}

// Round 11
// 1743.556 us; speedup vs baseline: 1.2989x; 1.0880x over previous
//
#include <hip/hip_runtime.h>
#include <cfloat>

#define NRW 32768
#define KC 4096
#define CD 256
#define HW 1024

// exact numpy fp32 MAC: scalar x times float4-over-codes e; mul & add separately rounded
#define MACS(accv, xsc, ev) do { \
  float p0 = (xsc) * (ev).x; (accv).x = (accv).x + p0; \
  float p1 = (xsc) * (ev).y; (accv).y = (accv).y + p1; \
  float p2 = (xsc) * (ev).z; (accv).z = (accv).z + p2; \
  float p3 = (xsc) * (ev).w; (accv).w = (accv).w + p3; } while (0)

// ---------- se[k] = np.sum(cb[k]**2) : numpy pairwise (128+128, scalar 8-acc) ----------
__global__ __launch_bounds__(256) void vq_se(const float* __restrict__ cb,
                                             float* __restrict__ se) {
#pragma clang fp contract(off)
  const int tid = threadIdx.x;
  const int g = tid >> 3;
  const int j = tid & 7;
  const int code = blockIdx.x * 32 + g;
  const float* e = cb + (size_t)code * CD;
  float half[2];
#pragma unroll
  for (int h = 0; h < 2; ++h) {
    const float* a = e + h * 128;
    float v = a[j];
    float r = v * v;
#pragma unroll
    for (int i = 1; i < 16; ++i) {
      float w = a[8 * i + j];
      float w2 = w * w;
      r = r + w2;
    }
    float l1 = r + __shfl_down(r, 1, 8);
    float l2 = l1 + __shfl_down(l1, 2, 8);
    float l3 = l2 + __shfl_down(l2, 4, 8);
    half[h] = l3;
  }
  if (j == 0) se[code] = half[0] + half[1];
}

// swizzled x LDS address: granule XOR by (row>>3)&3 spreads the 4 wave-distinct rows
__device__ __forceinline__ int xaddr(int row, int ch) {
  return row * 256 + ((((ch >> 2) ^ ((row >> 3) & 3)) << 2) | (ch & 3));
}

// one chunk step: publish st -> buf[PW], prefetch Q+2 -> st, compute buf[PR]
// chunk Q covers ch quads gq = 2*(tt^1)+1, 2*(tt^1)  (block-desc numpy order)
// wave-local chunk space: Q in [0, 512)  (16 code-groups x 32 chunks)
#define CHUNK_STEP(TT, PR, PW)                                                      \
  {                                                                                 \
    const int Q = cg * 32 + (TT);                                                   \
    if (Q < 511) {                                                                  \
      float* d = ebw + (PW) * 512 + lane;                                           \
      d[0]   = st0.x; d[64]  = st0.y; d[128] = st0.z; d[192] = st0.w;               \
      d[256] = st1.x; d[320] = st1.y; d[384] = st1.z; d[448] = st1.w;               \
    }                                                                               \
    if (Q < 510) {                                                                  \
      const int Q2 = Q + 2;                                                         \
      const float* src = cb + (size_t)(kwbase + (Q2 >> 5) * 64 + lane) * CD         \
                          + 8 * ((Q2 & 31) ^ 1);                                    \
      st0 = *(const float4*)(src);                                                  \
      st1 = *(const float4*)(src + 4);                                              \
    }                                                                               \
    const float* eb = ebw + (PR) * 512 + 4 * tx;                                    \
    const int u = (TT) ^ 1;                                                         \
    _Pragma("unroll")                                                               \
    for (int jq = 1; jq >= 0; --jq) {                                               \
      const float4 ev0 = *(const float4*)(eb + (4 * jq + 0) * 64);                  \
      const float4 ev1 = *(const float4*)(eb + (4 * jq + 1) * 64);                  \
      const float4 ev2 = *(const float4*)(eb + (4 * jq + 2) * 64);                  \
      const float4 ev3 = *(const float4*)(eb + (4 * jq + 3) * 64);                  \
      const int gq = 2 * u + jq;                                                    \
      float4 xv[8];                                                                 \
      _Pragma("unroll")                                                             \
      for (int r = 0; r < 8; ++r)                                                   \
        xv[r] = *(const float4*)(xs + (8 * ty + r) * 256 + ((gq ^ ty) << 2));       \
      _Pragma("unroll")                                                             \
      for (int r = 0; r < 8; ++r) {                                                 \
        MACS(acc[r][0], xv[r].x, ev0);                                              \
        MACS(acc[r][1], xv[r].y, ev1);                                              \
        MACS(acc[r][2], xv[r].z, ev2);                                              \
        MACS(acc[r][3], xv[r].w, ev3);                                              \
      }                                                                             \
    }                                                                               \
  }

// ---------- main: 32 rows in LDS; 2KB wave-private double-buffered e; no loop barriers ----------
__global__ __launch_bounds__(256) void vq_dist(const float* __restrict__ x,
                                               const float* __restrict__ cb,
                                               const float* __restrict__ se,
                                               float* __restrict__ outids) {
#pragma clang fp contract(off)
  __shared__ float xs[32 * 256];        // 32 KB, swizzled [row][ch]
  __shared__ float ebuf[4 * 2 * 512];   // 16 KB: 4 waves x 2 bufs x [8ch][64codes]
  __shared__ float sxs[32];
  __shared__ float mval[4 * 32];
  __shared__ int   midx[4 * 32];

  const int tid  = threadIdx.x;
  const int lane = tid & 63;
  const int wid  = tid >> 6;
  const int tx   = lane & 15;           // code quad within chunk
  const int ty   = lane >> 4;           // row group: rows 8ty..8ty+7
  const int b    = blockIdx.x >> 5;
  const int hw0  = (blockIdx.x & 31) << 5;
  const float* xb = x + (size_t)b * CD * HW + hw0;
  const int kwbase = wid << 10;         // wave's 1024-code range

  // ---- stage x once: thread = channel, 8 float4 over 32 rows ----
  {
    const float* src = xb + (size_t)tid * HW;
#pragma unroll
    for (int f = 0; f < 8; ++f) {
      const float4 v = *(const float4*)(src + 4 * f);
      xs[xaddr(4 * f + 0, tid)] = v.x;
      xs[xaddr(4 * f + 1, tid)] = v.y;
      xs[xaddr(4 * f + 2, tid)] = v.z;
      xs[xaddr(4 * f + 3, tid)] = v.w;
    }
  }
  __syncthreads();

  // ---- sx per row: numpy pairwise (128+128, scalar 8-acc), serial per thread ----
  if (tid < 32) {
    const int row = tid;
    float half[2];
#pragma unroll
    for (int h = 0; h < 2; ++h) {
      float racc[8];
#pragma unroll
      for (int j = 0; j < 8; ++j) {
        const float v = xs[xaddr(row, h * 128 + j)];
        racc[j] = v * v;
      }
#pragma unroll
      for (int i = 1; i < 16; ++i) {
#pragma unroll
        for (int j = 0; j < 8; ++j) {
          const float v = xs[xaddr(row, h * 128 + 8 * i + j)];
          const float v2 = v * v;
          racc[j] = racc[j] + v2;
        }
      }
      half[h] = ((racc[0] + racc[1]) + (racc[2] + racc[3])) +
                ((racc[4] + racc[5]) + (racc[6] + racc[7]));
    }
    sxs[row] = half[0] + half[1];
  }
  __syncthreads();

  float sxr[8];
#pragma unroll
  for (int r = 0; r < 8; ++r) sxr[r] = sxs[8 * ty + r];

  float* ebw = ebuf + wid * 1024;       // wave-private: 2 bufs x 512 floats

  // ---- prologue: Q=0 (tt=0 -> chb=8) into buf0; Q=1 (tt=1 -> chb=0) into regs ----
  float4 st0, st1;
  {
    const float* src = cb + (size_t)(kwbase + lane) * CD + 8;
    st0 = *(const float4*)(src);
    st1 = *(const float4*)(src + 4);
    float* d = ebw + lane;
    d[0]   = st0.x; d[64]  = st0.y; d[128] = st0.z; d[192] = st0.w;
    d[256] = st1.x; d[320] = st1.y; d[384] = st1.z; d[448] = st1.w;
    const float* s2 = cb + (size_t)(kwbase + lane) * CD;
    st0 = *(const float4*)(s2);
    st1 = *(const float4*)(s2 + 4);
  }

  float4 acc[8][4];                     // [row][SSE chain], float4 over 4 codes
  float m1[8];
  int   mi[8];
#pragma unroll
  for (int r = 0; r < 8; ++r) {
    m1[r] = FLT_MAX; mi[r] = 0;
#pragma unroll
    for (int l = 0; l < 4; ++l) { acc[r][l].x = 0.f; acc[r][l].y = 0.f; acc[r][l].z = 0.f; acc[r][l].w = 0.f; }
  }

#pragma unroll 1
  for (int cg = 0; cg < 16; ++cg) {
#pragma unroll 1
    for (int th = 0; th < 16; ++th) {
      CHUNK_STEP(2 * th,     0, 1);
      CHUNK_STEP(2 * th + 1, 1, 0);
    }
    // epilogue: SSE tree, sq = se+sx, dist = sq - 2*dot, running first-min
    const int kb = kwbase + cg * 64 + 4 * tx;
    const float4 se4 = *(const float4*)(se + kb);
#pragma unroll
    for (int r = 0; r < 8; ++r) {
      float4 dotv;
      dotv.x = (acc[r][0].x + acc[r][1].x) + (acc[r][2].x + acc[r][3].x);
      dotv.y = (acc[r][0].y + acc[r][1].y) + (acc[r][2].y + acc[r][3].y);
      dotv.z = (acc[r][0].z + acc[r][1].z) + (acc[r][2].z + acc[r][3].z);
      dotv.w = (acc[r][0].w + acc[r][1].w) + (acc[r][2].w + acc[r][3].w);
      const float d0 = (se4.x + sxr[r]) - 2.0f * dotv.x;
      const float d1 = (se4.y + sxr[r]) - 2.0f * dotv.y;
      const float d2 = (se4.z + sxr[r]) - 2.0f * dotv.z;
      const float d3 = (se4.w + sxr[r]) - 2.0f * dotv.w;
      if (d0 < m1[r]) { m1[r] = d0; mi[r] = kb; }
      if (d1 < m1[r]) { m1[r] = d1; mi[r] = kb + 1; }
      if (d2 < m1[r]) { m1[r] = d2; mi[r] = kb + 2; }
      if (d3 < m1[r]) { m1[r] = d3; mi[r] = kb + 3; }
#pragma unroll
      for (int l = 0; l < 4; ++l) { acc[r][l].x = 0.f; acc[r][l].y = 0.f; acc[r][l].z = 0.f; acc[r][l].w = 0.f; }
    }
  }

  // ---- merge: 16 lanes (same ty) per row, lexicographic; then 4 waves via LDS ----
#pragma unroll
  for (int r = 0; r < 8; ++r) {
    float v = m1[r];
    int   idx = mi[r];
#pragma unroll
    for (int off = 1; off < 16; off <<= 1) {
      const float ov = __shfl_xor(v, off, 16);
      const int   oi = __shfl_xor(idx, off, 16);
      if (ov < v || (ov == v && oi < idx)) { v = ov; idx = oi; }
    }
    if (tx == 0) {
      mval[wid * 32 + 8 * ty + r] = v;
      midx[wid * 32 + 8 * ty + r] = idx;
    }
  }
  __syncthreads();
  if (tid < 32) {
    float best = mval[tid];
    int   bi   = midx[tid];
#pragma unroll
    for (int ww = 1; ww < 4; ++ww) {
      const float v  = mval[ww * 32 + tid];
      const int   ix = midx[ww * 32 + tid];
      if (v < best || (v == best && ix < bi)) { best = v; bi = ix; }
    }
    outids[b * HW + hw0 + tid] = (float)bi;
  }
}

// ---------- emb gather ----------
__global__ __launch_bounds__(256) void vq_emb_out(const float* __restrict__ outids,
                                                  const float* __restrict__ cb,
                                                  float* __restrict__ out) {
  const int bx = blockIdx.x;
  const int b = bx >> 10;
  const int rem = bx & 1023;
  const int c = rem >> 2;
  const int q = rem & 3;
  const int hw = q * 256 + threadIdx.x;
  const int id = (int)outids[b * HW + hw];
  out[((size_t)(b * CD + c)) * HW + hw] = cb[(size_t)id * CD + c];
}

extern "C" void kernel_launch(void* const* d_in, const int* in_sizes, int n_in,
                              void* d_out, int out_size, void* d_ws, size_t ws_size,
                              hipStream_t stream) {
  const float* x  = (const float*)d_in[0];   // (32,256,32,32) f32
  const float* cb = (const float*)d_in[1];   // (4096,256) f32
  float* out = (float*)d_out;                // [0..32767]=ids, [32768..]=emb

  float* se = (float*)d_ws;                  // 16 KB

  vq_se<<<KC / 32, 256, 0, stream>>>(cb, se);
  vq_dist<<<NRW / 32, 256, 0, stream>>>(x, cb, se, out);
  vq_emb_out<<<32768, 256, 0, stream>>>(out, cb, out + NRW);
}

// Round 12
// 1569.070 us; speedup vs baseline: 1.4433x; 1.1112x over previous
//
#include <hip/hip_runtime.h>
#include <cfloat>

#define NRW 32768
#define KC 4096
#define CD 256
#define HW 1024

// exact numpy fp32 MAC: scalar x times float4-over-codes e; mul & add separately rounded
#define MACS(accv, xsc, ev) do { \
  float p0 = (xsc) * (ev).x; (accv).x = (accv).x + p0; \
  float p1 = (xsc) * (ev).y; (accv).y = (accv).y + p1; \
  float p2 = (xsc) * (ev).z; (accv).z = (accv).z + p2; \
  float p3 = (xsc) * (ev).w; (accv).w = (accv).w + p3; } while (0)

// ---------- se[k] = np.sum(cb[k]**2) : numpy pairwise (128+128, scalar 8-acc) ----------
__global__ __launch_bounds__(256) void vq_se(const float* __restrict__ cb,
                                             float* __restrict__ se) {
#pragma clang fp contract(off)
  const int tid = threadIdx.x;
  const int g = tid >> 3;
  const int j = tid & 7;
  const int code = blockIdx.x * 32 + g;
  const float* e = cb + (size_t)code * CD;
  float half[2];
#pragma unroll
  for (int h = 0; h < 2; ++h) {
    const float* a = e + h * 128;
    float v = a[j];
    float r = v * v;
#pragma unroll
    for (int i = 1; i < 16; ++i) {
      float w = a[8 * i + j];
      float w2 = w * w;
      r = r + w2;
    }
    float l1 = r + __shfl_down(r, 1, 8);
    float l2 = l1 + __shfl_down(l1, 2, 8);
    float l3 = l2 + __shfl_down(l2, 4, 8);
    half[h] = l3;
  }
  if (j == 0) se[code] = half[0] + half[1];
}

// swizzled x LDS address: granule XOR by (row>>2)&3 spreads the 4 wave-distinct rows
__device__ __forceinline__ int xaddr(int row, int ch) {
  return row * 256 + ((((ch >> 2) ^ ((row >> 2) & 3)) << 2) | (ch & 3));
}

// one chunk step: publish st -> buf[PW], prefetch Q+2 -> st, compute buf[PR]
// chunk Q covers ch quads gq = 2*(tt^1)+1, 2*(tt^1)  (numpy 16-ch blocks asc, j=3..0)
// wave-local chunk space: Q in [0, 512)  (16 code-groups x 32 chunks)
#define CHUNK_STEP(TT, PR, PW)                                                      \
  {                                                                                 \
    const int Q = cg * 32 + (TT);                                                   \
    if (Q < 511) {                                                                  \
      float* d = ebw + (PW) * 512 + lane;                                           \
      d[0]   = st0.x; d[64]  = st0.y; d[128] = st0.z; d[192] = st0.w;               \
      d[256] = st1.x; d[320] = st1.y; d[384] = st1.z; d[448] = st1.w;               \
    }                                                                               \
    if (Q < 510) {                                                                  \
      const int Q2 = Q + 2;                                                         \
      const float* src = cb + (size_t)(kwbase + (Q2 >> 5) * 64 + lane) * CD         \
                          + 8 * ((Q2 & 31) ^ 1);                                    \
      st0 = *(const float4*)(src);                                                  \
      st1 = *(const float4*)(src + 4);                                              \
    }                                                                               \
    const float* eb = ebw + (PR) * 512 + 4 * tx;                                    \
    const int u = (TT) ^ 1;                                                         \
    _Pragma("unroll")                                                               \
    for (int jq = 1; jq >= 0; --jq) {                                               \
      const float4 ev0 = *(const float4*)(eb + (4 * jq + 0) * 64);                  \
      const float4 ev1 = *(const float4*)(eb + (4 * jq + 1) * 64);                  \
      const float4 ev2 = *(const float4*)(eb + (4 * jq + 2) * 64);                  \
      const float4 ev3 = *(const float4*)(eb + (4 * jq + 3) * 64);                  \
      const int gq = 2 * u + jq;                                                    \
      float4 xv[4];                                                                 \
      _Pragma("unroll")                                                             \
      for (int r = 0; r < 4; ++r)                                                   \
        xv[r] = *(const float4*)(xs + (4 * ty + r) * 256 + ((gq ^ ty) << 2));       \
      _Pragma("unroll")                                                             \
      for (int r = 0; r < 4; ++r) {                                                 \
        MACS(acc[r][0], xv[r].x, ev0);                                              \
        MACS(acc[r][1], xv[r].y, ev1);                                              \
        MACS(acc[r][2], xv[r].z, ev2);                                              \
        MACS(acc[r][3], xv[r].w, ev3);                                              \
      }                                                                             \
    }                                                                               \
  }

// ---------- main: 16 rows in LDS; 2KB wave-private double-buffered e; no loop barriers ----------
__global__ __launch_bounds__(256) void vq_dist(const float* __restrict__ x,
                                               const float* __restrict__ cb,
                                               const float* __restrict__ se,
                                               float* __restrict__ outids) {
#pragma clang fp contract(off)
  __shared__ float xs[16 * 256];        // 16 KB, swizzled [row][ch]
  __shared__ float ebuf[4 * 2 * 512];   // 16 KB: 4 waves x 2 bufs x [8ch][64codes]
  __shared__ float sxs[16];
  __shared__ float mval[4 * 16];
  __shared__ int   midx[4 * 16];

  const int tid  = threadIdx.x;
  const int lane = tid & 63;
  const int wid  = tid >> 6;
  const int tx   = lane & 15;           // code quad within chunk
  const int ty   = lane >> 4;           // row group: rows 4ty..4ty+3
  const int b    = blockIdx.x >> 6;
  const int hw0  = (blockIdx.x & 63) << 4;
  const float* xb = x + (size_t)b * CD * HW + hw0;
  const int kwbase = wid << 10;         // wave's 1024-code range

  // ---- stage x once: thread = channel, 4 float4 over 16 rows ----
  {
    const float* src = xb + (size_t)tid * HW;
#pragma unroll
    for (int f = 0; f < 4; ++f) {
      const float4 v = *(const float4*)(src + 4 * f);
      xs[xaddr(4 * f + 0, tid)] = v.x;
      xs[xaddr(4 * f + 1, tid)] = v.y;
      xs[xaddr(4 * f + 2, tid)] = v.z;
      xs[xaddr(4 * f + 3, tid)] = v.w;
    }
  }
  __syncthreads();

  // ---- sx per row: numpy pairwise (128+128, scalar 8-acc), serial per thread ----
  if (tid < 16) {
    const int row = tid;
    float half[2];
#pragma unroll
    for (int h = 0; h < 2; ++h) {
      float racc[8];
#pragma unroll
      for (int j = 0; j < 8; ++j) {
        const float v = xs[xaddr(row, h * 128 + j)];
        racc[j] = v * v;
      }
#pragma unroll
      for (int i = 1; i < 16; ++i) {
#pragma unroll
        for (int j = 0; j < 8; ++j) {
          const float v = xs[xaddr(row, h * 128 + 8 * i + j)];
          const float v2 = v * v;
          racc[j] = racc[j] + v2;
        }
      }
      half[h] = ((racc[0] + racc[1]) + (racc[2] + racc[3])) +
                ((racc[4] + racc[5]) + (racc[6] + racc[7]));
    }
    sxs[row] = half[0] + half[1];
  }
  __syncthreads();

  float sxr[4];
#pragma unroll
  for (int r = 0; r < 4; ++r) sxr[r] = sxs[4 * ty + r];

  float* ebw = ebuf + wid * 1024;       // wave-private: 2 bufs x 512 floats

  // ---- prologue: chunk 0 (ch 8..15) into buf0; chunk 1 (ch 0..7) into regs ----
  float4 st0, st1;
  {
    const float* src = cb + (size_t)(kwbase + lane) * CD + 8;
    st0 = *(const float4*)(src);
    st1 = *(const float4*)(src + 4);
    float* d = ebw + lane;
    d[0]   = st0.x; d[64]  = st0.y; d[128] = st0.z; d[192] = st0.w;
    d[256] = st1.x; d[320] = st1.y; d[384] = st1.z; d[448] = st1.w;
    const float* s2 = cb + (size_t)(kwbase + lane) * CD;
    st0 = *(const float4*)(s2);
    st1 = *(const float4*)(s2 + 4);
  }

  float4 acc[4][4];                     // [row][SSE chain], float4 over 4 codes
  float m1[4];
  int   mi[4];
#pragma unroll
  for (int r = 0; r < 4; ++r) {
    m1[r] = FLT_MAX; mi[r] = 0;
#pragma unroll
    for (int l = 0; l < 4; ++l) { acc[r][l].x = 0.f; acc[r][l].y = 0.f; acc[r][l].z = 0.f; acc[r][l].w = 0.f; }
  }

#pragma unroll 1
  for (int cg = 0; cg < 16; ++cg) {
#pragma unroll 1
    for (int th = 0; th < 16; ++th) {
      CHUNK_STEP(2 * th,     0, 1);
      CHUNK_STEP(2 * th + 1, 1, 0);
    }
    // epilogue: SSE tree, sq = se+sx, dist = sq - 2*dot, running first-min
    const int kb = kwbase + cg * 64 + 4 * tx;
    const float4 se4 = *(const float4*)(se + kb);
#pragma unroll
    for (int r = 0; r < 4; ++r) {
      float4 dotv;
      dotv.x = (acc[r][0].x + acc[r][1].x) + (acc[r][2].x + acc[r][3].x);
      dotv.y = (acc[r][0].y + acc[r][1].y) + (acc[r][2].y + acc[r][3].y);
      dotv.z = (acc[r][0].z + acc[r][1].z) + (acc[r][2].z + acc[r][3].z);
      dotv.w = (acc[r][0].w + acc[r][1].w) + (acc[r][2].w + acc[r][3].w);
      const float d0 = (se4.x + sxr[r]) - 2.0f * dotv.x;
      const float d1 = (se4.y + sxr[r]) - 2.0f * dotv.y;
      const float d2 = (se4.z + sxr[r]) - 2.0f * dotv.z;
      const float d3 = (se4.w + sxr[r]) - 2.0f * dotv.w;
      if (d0 < m1[r]) { m1[r] = d0; mi[r] = kb; }
      if (d1 < m1[r]) { m1[r] = d1; mi[r] = kb + 1; }
      if (d2 < m1[r]) { m1[r] = d2; mi[r] = kb + 2; }
      if (d3 < m1[r]) { m1[r] = d3; mi[r] = kb + 3; }
#pragma unroll
      for (int l = 0; l < 4; ++l) { acc[r][l].x = 0.f; acc[r][l].y = 0.f; acc[r][l].z = 0.f; acc[r][l].w = 0.f; }
    }
  }

  // ---- merge: 16 lanes (same ty) per row, lexicographic; then 4 waves via LDS ----
#pragma unroll
  for (int r = 0; r < 4; ++r) {
    float v = m1[r];
    int   idx = mi[r];
#pragma unroll
    for (int off = 1; off < 16; off <<= 1) {
      const float ov = __shfl_xor(v, off, 16);
      const int   oi = __shfl_xor(idx, off, 16);
      if (ov < v || (ov == v && oi < idx)) { v = ov; idx = oi; }
    }
    if (tx == 0) {
      mval[wid * 16 + 4 * ty + r] = v;
      midx[wid * 16 + 4 * ty + r] = idx;
    }
  }
  __syncthreads();
  if (tid < 16) {
    float best = mval[tid];
    int   bi   = midx[tid];
#pragma unroll
    for (int ww = 1; ww < 4; ++ww) {
      const float v  = mval[ww * 16 + tid];
      const int   ix = midx[ww * 16 + tid];
      if (v < best || (v == best && ix < bi)) { best = v; bi = ix; }
    }
    outids[b * HW + hw0 + tid] = (float)bi;
  }
}

// ---------- emb gather ----------
__global__ __launch_bounds__(256) void vq_emb_out(const float* __restrict__ outids,
                                                  const float* __restrict__ cb,
                                                  float* __restrict__ out) {
  const int bx = blockIdx.x;
  const int b = bx >> 10;
  const int rem = bx & 1023;
  const int c = rem >> 2;
  const int q = rem & 3;
  const int hw = q * 256 + threadIdx.x;
  const int id = (int)outids[b * HW + hw];
  out[((size_t)(b * CD + c)) * HW + hw] = cb[(size_t)id * CD + c];
}

extern "C" void kernel_launch(void* const* d_in, const int* in_sizes, int n_in,
                              void* d_out, int out_size, void* d_ws, size_t ws_size,
                              hipStream_t stream) {
  const float* x  = (const float*)d_in[0];   // (32,256,32,32) f32
  const float* cb = (const float*)d_in[1];   // (4096,256) f32
  float* out = (float*)d_out;                // [0..32767]=ids, [32768..]=emb

  float* se = (float*)d_ws;                  // 16 KB

  vq_se<<<KC / 32, 256, 0, stream>>>(cb, se);
  vq_dist<<<NRW / 16, 256, 0, stream>>>(x, cb, se, out);
  vq_emb_out<<<32768, 256, 0, stream>>>(out, cb, out + NRW);
}

// Round 13
// 1559.945 us; speedup vs baseline: 1.4518x; 1.0058x over previous
//
#include <hip/hip_runtime.h>
#include <cfloat>

#define NRW 32768
#define KC 4096
#define CD 256
#define HW 1024

typedef float f2 __attribute__((ext_vector_type(2)));

// packed MAC pair: acc(a0=codes01, a1=codes23) += x_comp_L * e_quad
// v_pk_*_f32: per-component IEEE fp32 mul/add, same rounding as scalar -> bit-exact
template <int L>
__device__ __forceinline__ void pkmac(f2& a0, f2& a1, const float4& xq, const float4& eq) {
  union U { float4 q; f2 h[2]; };
  U xu; xu.q = xq;
  U eu; eu.q = eq;
  f2 p;
  if constexpr ((L & 1) == 0) {
    asm("v_pk_mul_f32 %0, %1, %2 op_sel:[0,0] op_sel_hi:[0,1]" : "=v"(p) : "v"(xu.h[L >> 1]), "v"(eu.h[0]));
  } else {
    asm("v_pk_mul_f32 %0, %1, %2 op_sel:[1,0] op_sel_hi:[1,1]" : "=v"(p) : "v"(xu.h[L >> 1]), "v"(eu.h[0]));
  }
  asm("v_pk_add_f32 %0, %0, %1" : "+v"(a0) : "v"(p));
  if constexpr ((L & 1) == 0) {
    asm("v_pk_mul_f32 %0, %1, %2 op_sel:[0,0] op_sel_hi:[0,1]" : "=v"(p) : "v"(xu.h[L >> 1]), "v"(eu.h[1]));
  } else {
    asm("v_pk_mul_f32 %0, %1, %2 op_sel:[1,0] op_sel_hi:[1,1]" : "=v"(p) : "v"(xu.h[L >> 1]), "v"(eu.h[1]));
  }
  asm("v_pk_add_f32 %0, %0, %1" : "+v"(a1) : "v"(p));
}

// ---------- se[k] = np.sum(cb[k]**2) : numpy pairwise (128+128, scalar 8-acc) ----------
__global__ __launch_bounds__(256) void vq_se(const float* __restrict__ cb,
                                             float* __restrict__ se) {
#pragma clang fp contract(off)
  const int tid = threadIdx.x;
  const int g = tid >> 3;
  const int j = tid & 7;
  const int code = blockIdx.x * 32 + g;
  const float* e = cb + (size_t)code * CD;
  float half[2];
#pragma unroll
  for (int h = 0; h < 2; ++h) {
    const float* a = e + h * 128;
    float v = a[j];
    float r = v * v;
#pragma unroll
    for (int i = 1; i < 16; ++i) {
      float w = a[8 * i + j];
      float w2 = w * w;
      r = r + w2;
    }
    float l1 = r + __shfl_down(r, 1, 8);
    float l2 = l1 + __shfl_down(l1, 2, 8);
    float l3 = l2 + __shfl_down(l2, 4, 8);
    half[h] = l3;
  }
  if (j == 0) se[code] = half[0] + half[1];
}

// swizzled x LDS address: granule XOR by (row>>2)&3 spreads the 4 wave-distinct rows
__device__ __forceinline__ int xaddr(int row, int ch) {
  return row * 256 + ((((ch >> 2) ^ ((row >> 2) & 3)) << 2) | (ch & 3));
}

// one chunk step: publish st -> buf[PW], prefetch Q+2 -> st, compute buf[PR]
// chunk Q covers ch quads gq = 2*(tt^1)+1, 2*(tt^1)  (numpy 16-ch blocks asc, j=3..0)
// wave-local chunk space: Q in [0, 512)  (16 code-groups x 32 chunks)
#define CHUNK_STEP(TT, PR, PW)                                                      \
  {                                                                                 \
    const int Q = cg * 32 + (TT);                                                   \
    if (Q < 511) {                                                                  \
      float* d = ebw + (PW) * 512 + lane;                                           \
      d[0]   = st0.x; d[64]  = st0.y; d[128] = st0.z; d[192] = st0.w;               \
      d[256] = st1.x; d[320] = st1.y; d[384] = st1.z; d[448] = st1.w;               \
    }                                                                               \
    if (Q < 510) {                                                                  \
      const int Q2 = Q + 2;                                                         \
      const float* src = cb + (size_t)(kwbase + (Q2 >> 5) * 64 + lane) * CD         \
                          + 8 * ((Q2 & 31) ^ 1);                                    \
      st0 = *(const float4*)(src);                                                  \
      st1 = *(const float4*)(src + 4);                                              \
    }                                                                               \
    const float* eb = ebw + (PR) * 512 + 4 * tx;                                    \
    const int u = (TT) ^ 1;                                                         \
    _Pragma("unroll")                                                               \
    for (int jq = 1; jq >= 0; --jq) {                                               \
      const float4 ev0 = *(const float4*)(eb + (4 * jq + 0) * 64);                  \
      const float4 ev1 = *(const float4*)(eb + (4 * jq + 1) * 64);                  \
      const float4 ev2 = *(const float4*)(eb + (4 * jq + 2) * 64);                  \
      const float4 ev3 = *(const float4*)(eb + (4 * jq + 3) * 64);                  \
      const int gq = 2 * u + jq;                                                    \
      _Pragma("unroll")                                                             \
      for (int r = 0; r < 4; ++r) {                                                 \
        const float4 xv = *(const float4*)(xs + (4 * ty + r) * 256 + ((gq ^ ty) << 2)); \
        pkmac<0>(acc[r][0][0], acc[r][0][1], xv, ev0);                              \
        pkmac<1>(acc[r][1][0], acc[r][1][1], xv, ev1);                              \
        pkmac<2>(acc[r][2][0], acc[r][2][1], xv, ev2);                              \
        pkmac<3>(acc[r][3][0], acc[r][3][1], xv, ev3);                              \
      }                                                                             \
    }                                                                               \
  }

// ---------- main: 16 rows in LDS; 2KB wave-private double-buffered e; no loop barriers ----------
__global__ __launch_bounds__(256) void vq_dist(const float* __restrict__ x,
                                               const float* __restrict__ cb,
                                               const float* __restrict__ se,
                                               float* __restrict__ outids) {
#pragma clang fp contract(off)
  __shared__ float xs[16 * 256];        // 16 KB, swizzled [row][ch]
  __shared__ float ebuf[4 * 2 * 512];   // 16 KB: 4 waves x 2 bufs x [8ch][64codes]
  __shared__ float sxs[16];
  __shared__ float mval[4 * 16];
  __shared__ int   midx[4 * 16];

  const int tid  = threadIdx.x;
  const int lane = tid & 63;
  const int wid  = tid >> 6;
  const int tx   = lane & 15;           // code quad within chunk
  const int ty   = lane >> 4;           // row group: rows 4ty..4ty+3
  const int b    = blockIdx.x >> 6;
  const int hw0  = (blockIdx.x & 63) << 4;
  const float* xb = x + (size_t)b * CD * HW + hw0;
  const int kwbase = wid << 10;         // wave's 1024-code range

  // ---- stage x once: thread = channel, 4 float4 over 16 rows ----
  {
    const float* src = xb + (size_t)tid * HW;
#pragma unroll
    for (int f = 0; f < 4; ++f) {
      const float4 v = *(const float4*)(src + 4 * f);
      xs[xaddr(4 * f + 0, tid)] = v.x;
      xs[xaddr(4 * f + 1, tid)] = v.y;
      xs[xaddr(4 * f + 2, tid)] = v.z;
      xs[xaddr(4 * f + 3, tid)] = v.w;
    }
  }
  __syncthreads();

  // ---- sx per row: numpy pairwise (128+128, scalar 8-acc), serial per thread ----
  if (tid < 16) {
    const int row = tid;
    float half[2];
#pragma unroll
    for (int h = 0; h < 2; ++h) {
      float racc[8];
#pragma unroll
      for (int j = 0; j < 8; ++j) {
        const float v = xs[xaddr(row, h * 128 + j)];
        racc[j] = v * v;
      }
#pragma unroll
      for (int i = 1; i < 16; ++i) {
#pragma unroll
        for (int j = 0; j < 8; ++j) {
          const float v = xs[xaddr(row, h * 128 + 8 * i + j)];
          const float v2 = v * v;
          racc[j] = racc[j] + v2;
        }
      }
      half[h] = ((racc[0] + racc[1]) + (racc[2] + racc[3])) +
                ((racc[4] + racc[5]) + (racc[6] + racc[7]));
    }
    sxs[row] = half[0] + half[1];
  }
  __syncthreads();

  float sxr[4];
#pragma unroll
  for (int r = 0; r < 4; ++r) sxr[r] = sxs[4 * ty + r];

  float* ebw = ebuf + wid * 1024;       // wave-private: 2 bufs x 512 floats

  // ---- prologue: chunk 0 (ch 8..15) into buf0; chunk 1 (ch 0..7) into regs ----
  float4 st0, st1;
  {
    const float* src = cb + (size_t)(kwbase + lane) * CD + 8;
    st0 = *(const float4*)(src);
    st1 = *(const float4*)(src + 4);
    float* d = ebw + lane;
    d[0]   = st0.x; d[64]  = st0.y; d[128] = st0.z; d[192] = st0.w;
    d[256] = st1.x; d[320] = st1.y; d[384] = st1.z; d[448] = st1.w;
    const float* s2 = cb + (size_t)(kwbase + lane) * CD;
    st0 = *(const float4*)(s2);
    st1 = *(const float4*)(s2 + 4);
  }

  f2 acc[4][4][2];                      // [row][SSE chain][code pair]
  float m1[4];
  int   mi[4];
#pragma unroll
  for (int r = 0; r < 4; ++r) {
    m1[r] = FLT_MAX; mi[r] = 0;
#pragma unroll
    for (int l = 0; l < 4; ++l) {
      acc[r][l][0] = (f2){0.f, 0.f};
      acc[r][l][1] = (f2){0.f, 0.f};
    }
  }

#pragma unroll 1
  for (int cg = 0; cg < 16; ++cg) {
#pragma unroll 1
    for (int th = 0; th < 16; ++th) {
      CHUNK_STEP(2 * th,     0, 1);
      CHUNK_STEP(2 * th + 1, 1, 0);
    }
    // epilogue: SSE tree, sq = se+sx, dist = sq - 2*dot, running first-min
    const int kb = kwbase + cg * 64 + 4 * tx;
    const float4 se4 = *(const float4*)(se + kb);
#pragma unroll
    for (int r = 0; r < 4; ++r) {
      const float dot0 = (acc[r][0][0].x + acc[r][1][0].x) + (acc[r][2][0].x + acc[r][3][0].x);
      const float dot1 = (acc[r][0][0].y + acc[r][1][0].y) + (acc[r][2][0].y + acc[r][3][0].y);
      const float dot2 = (acc[r][0][1].x + acc[r][1][1].x) + (acc[r][2][1].x + acc[r][3][1].x);
      const float dot3 = (acc[r][0][1].y + acc[r][1][1].y) + (acc[r][2][1].y + acc[r][3][1].y);
      const float d0 = (se4.x + sxr[r]) - 2.0f * dot0;
      const float d1 = (se4.y + sxr[r]) - 2.0f * dot1;
      const float d2 = (se4.z + sxr[r]) - 2.0f * dot2;
      const float d3 = (se4.w + sxr[r]) - 2.0f * dot3;
      if (d0 < m1[r]) { m1[r] = d0; mi[r] = kb; }
      if (d1 < m1[r]) { m1[r] = d1; mi[r] = kb + 1; }
      if (d2 < m1[r]) { m1[r] = d2; mi[r] = kb + 2; }
      if (d3 < m1[r]) { m1[r] = d3; mi[r] = kb + 3; }
#pragma unroll
      for (int l = 0; l < 4; ++l) {
        acc[r][l][0] = (f2){0.f, 0.f};
        acc[r][l][1] = (f2){0.f, 0.f};
      }
    }
  }

  // ---- merge: 16 lanes (same ty) per row, lexicographic; then 4 waves via LDS ----
#pragma unroll
  for (int r = 0; r < 4; ++r) {
    float v = m1[r];
    int   idx = mi[r];
#pragma unroll
    for (int off = 1; off < 16; off <<= 1) {
      const float ov = __shfl_xor(v, off, 16);
      const int   oi = __shfl_xor(idx, off, 16);
      if (ov < v || (ov == v && oi < idx)) { v = ov; idx = oi; }
    }
    if (tx == 0) {
      mval[wid * 16 + 4 * ty + r] = v;
      midx[wid * 16 + 4 * ty + r] = idx;
    }
  }
  __syncthreads();
  if (tid < 16) {
    float best = mval[tid];
    int   bi   = midx[tid];
#pragma unroll
    for (int ww = 1; ww < 4; ++ww) {
      const float v  = mval[ww * 16 + tid];
      const int   ix = midx[ww * 16 + tid];
      if (v < best || (v == best && ix < bi)) { best = v; bi = ix; }
    }
    outids[b * HW + hw0 + tid] = (float)bi;
  }
}

// ---------- emb gather ----------
__global__ __launch_bounds__(256) void vq_emb_out(const float* __restrict__ outids,
                                                  const float* __restrict__ cb,
                                                  float* __restrict__ out) {
  const int bx = blockIdx.x;
  const int b = bx >> 10;
  const int rem = bx & 1023;
  const int c = rem >> 2;
  const int q = rem & 3;
  const int hw = q * 256 + threadIdx.x;
  const int id = (int)outids[b * HW + hw];
  out[((size_t)(b * CD + c)) * HW + hw] = cb[(size_t)id * CD + c];
}

extern "C" void kernel_launch(void* const* d_in, const int* in_sizes, int n_in,
                              void* d_out, int out_size, void* d_ws, size_t ws_size,
                              hipStream_t stream) {
  const float* x  = (const float*)d_in[0];   // (32,256,32,32) f32
  const float* cb = (const float*)d_in[1];   // (4096,256) f32
  float* out = (float*)d_out;                // [0..32767]=ids, [32768..]=emb

  float* se = (float*)d_ws;                  // 16 KB

  vq_se<<<KC / 32, 256, 0, stream>>>(cb, se);
  vq_dist<<<NRW / 16, 256, 0, stream>>>(x, cb, se, out);
  vq_emb_out<<<32768, 256, 0, stream>>>(out, cb, out + NRW);
}

// Round 14
// 540.930 us; speedup vs baseline: 4.1866x; 2.8838x over previous
//
#include <hip/hip_runtime.h>
#include <cfloat>

#define NRW 32768
#define KC 4096
#define CD 256
#define HW 1024
#define CAP 64
#define WIN 1e-3f

typedef short bf16x8 __attribute__((ext_vector_type(8)));
typedef float f32x4 __attribute__((ext_vector_type(4)));

__device__ __forceinline__ unsigned short f2bf(float f) {  // RNE f32->bf16
  unsigned int u = __float_as_uint(f);
  u = (u + 0x7FFFu + ((u >> 16) & 1u)) >> 16;
  return (unsigned short)u;
}

// ---------- se[k] = np.sum(cb[k]**2) : numpy pairwise (128+128, scalar 8-acc) [verified] ----------
__global__ __launch_bounds__(256) void vq_se(const float* __restrict__ cb,
                                             float* __restrict__ se) {
#pragma clang fp contract(off)
  const int tid = threadIdx.x;
  const int g = tid >> 3;
  const int j = tid & 7;
  const int code = blockIdx.x * 32 + g;
  const float* e = cb + (size_t)code * CD;
  float half[2];
#pragma unroll
  for (int h = 0; h < 2; ++h) {
    const float* a = e + h * 128;
    float v = a[j];
    float r = v * v;
#pragma unroll
    for (int i = 1; i < 16; ++i) {
      float w = a[8 * i + j];
      float w2 = w * w;
      r = r + w2;
    }
    float l1 = r + __shfl_down(r, 1, 8);
    float l2 = l1 + __shfl_down(l1, 2, 8);
    float l3 = l2 + __shfl_down(l2, 4, 8);
    half[h] = l3;
  }
  if (j == 0) se[code] = half[0] + half[1];
}

// ---------- convert x (B,C,H,W) f32 -> xh[row][ch] bf16 (transpose, RNE) ----------
__global__ __launch_bounds__(256) void vq_cvt_x(const float* __restrict__ x,
                                                unsigned short* __restrict__ xh) {
  const int t = threadIdx.x;                  // channel
  const int b = blockIdx.x >> 4;
  const int hw0 = (blockIdx.x & 15) << 6;
  const float* src = x + ((size_t)b * CD + t) * HW + hw0;
  unsigned short* dst = xh + ((size_t)b * HW + hw0) * CD + t;
#pragma unroll
  for (int f = 0; f < 16; ++f) {
    const float4 v = *(const float4*)(src + 4 * f);
    dst[(size_t)(4 * f + 0) * CD] = f2bf(v.x);
    dst[(size_t)(4 * f + 1) * CD] = f2bf(v.y);
    dst[(size_t)(4 * f + 2) * CD] = f2bf(v.z);
    dst[(size_t)(4 * f + 3) * CD] = f2bf(v.w);
  }
}

// ---------- convert cb f32 -> eh bf16 (flat) ----------
__global__ __launch_bounds__(256) void vq_cvt_e(const float* __restrict__ cb,
                                                unsigned short* __restrict__ eh) {
  const int i4 = (blockIdx.x * 256 + threadIdx.x) * 4;
  const float4 v = *(const float4*)(cb + i4);
  ushort4 o;
  o.x = f2bf(v.x); o.y = f2bf(v.y); o.z = f2bf(v.z); o.w = f2bf(v.w);
  *(ushort4*)(eh + i4) = o;
}

// ---------- MFMA filter GEMM: 64 rows/block, stream 64-code groups ----------
// wave w: rows (w&1)*32 .. +32 (two 16-slabs), code half (w>>1)*32 of each cg
// PASS 1: per-row filter min -> minv, zero cnt/nflg.  PASS 2: collect s' <= minv+WIN.
template <int PASS>
__global__ __launch_bounds__(256) void vq_gemm(const unsigned short* __restrict__ xh,
                                               const unsigned short* __restrict__ eh,
                                               const float* __restrict__ se,
                                               float* __restrict__ minv,
                                               int* __restrict__ cnt,
                                               int* __restrict__ nflg,
                                               int* __restrict__ cand) {
  __shared__ unsigned short es[64 * 256];     // 32 KB, swizzled [code][ch]
  __shared__ float mval[2][64];

  const int t = threadIdx.x;
  const int l = t & 63;
  const int w = t >> 6;
  const int rs = (w & 1) * 32;                // row-slab base within block
  const int ch32 = (w >> 1) * 32;             // code half within cg
  const int rowbase = blockIdx.x * 64;
  const int lq = l >> 4;                      // lane quad 0..3
  const int ll = l & 15;

  // A fragments: 2 slabs x 8 kb, direct from global (coalesced 64B lines)
  bf16x8 afr[2][8];
#pragma unroll
  for (int mt = 0; mt < 2; ++mt) {
    const unsigned short* ga = xh + (size_t)(rowbase + rs + 16 * mt + ll) * CD + (lq << 3);
#pragma unroll
    for (int kb = 0; kb < 8; ++kb)
      afr[mt][kb] = *(const bf16x8*)(ga + (kb << 5));
  }

  float run[2][4], thr[2][4];
#pragma unroll
  for (int mt = 0; mt < 2; ++mt)
#pragma unroll
    for (int r = 0; r < 4; ++r) run[mt][r] = FLT_MAX;
  if (PASS == 2) {
#pragma unroll
    for (int mt = 0; mt < 2; ++mt)
#pragma unroll
      for (int r = 0; r < 4; ++r)
        thr[mt][r] = minv[rowbase + rs + 16 * mt + 4 * lq + r] + WIN;
  }

#pragma unroll 1
  for (int cg = 0; cg < 64; ++cg) {
    // stage eh cg-tile into swizzled LDS
    {
      const int co = t >> 2, seg = t & 3;
      const unsigned short* g = eh + (size_t)(cg * 64 + co) * CD + seg * 64;
      const int sw = co & 7;
#pragma unroll
      for (int u = 0; u < 8; ++u) {
        const uint4 v = *(const uint4*)(g + u * 8);
        const int c8 = seg * 8 + u;
        *(uint4*)&es[co * 256 + ((c8 ^ sw) << 3)] = v;
      }
    }
    __syncthreads();

    f32x4 acc[2][2];
#pragma unroll
    for (int mt = 0; mt < 2; ++mt)
#pragma unroll
      for (int nt = 0; nt < 2; ++nt) acc[mt][nt] = (f32x4){0.f, 0.f, 0.f, 0.f};

#pragma unroll
    for (int kb = 0; kb < 8; ++kb) {
#pragma unroll
      for (int nt = 0; nt < 2; ++nt) {
        const int col = ch32 + 16 * nt + ll;
        const int c8 = (kb << 2) + lq;
        const bf16x8 bfr = *(const bf16x8*)&es[col * 256 + ((c8 ^ (col & 7)) << 3)];
        acc[0][nt] = __builtin_amdgcn_mfma_f32_16x16x32_bf16(afr[0][kb], bfr, acc[0][nt], 0, 0, 0);
        acc[1][nt] = __builtin_amdgcn_mfma_f32_16x16x32_bf16(afr[1][kb], bfr, acc[1][nt], 0, 0, 0);
      }
    }

    // epilogue: s' = se - 2*dot (filter score; no sx needed for per-row argmin)
#pragma unroll
    for (int nt = 0; nt < 2; ++nt) {
      const int code = cg * 64 + ch32 + 16 * nt + ll;
      const float sev = se[code];
#pragma unroll
      for (int mt = 0; mt < 2; ++mt) {
#pragma unroll
        for (int r = 0; r < 4; ++r) {
          const float s = sev - 2.0f * acc[mt][nt][r];
          if (PASS == 1) {
            if (s < run[mt][r]) run[mt][r] = s;
          } else {
            if (s <= thr[mt][r]) {
              const int row = rowbase + rs + 16 * mt + 4 * lq + r;
              const int pos = atomicAdd(&cnt[row], 1);
              if (pos < CAP) cand[(size_t)row * CAP + pos] = code;
            }
          }
        }
      }
    }
    __syncthreads();
  }

  if (PASS == 1) {
    // reduce across 16 lanes (cols), then merge the two code-halves via LDS
#pragma unroll
    for (int mt = 0; mt < 2; ++mt)
#pragma unroll
      for (int r = 0; r < 4; ++r) {
        float v = run[mt][r];
#pragma unroll
        for (int off = 1; off < 16; off <<= 1) v = fminf(v, __shfl_xor(v, off, 16));
        if (ll == 0) mval[w >> 1][rs + 16 * mt + 4 * lq + r] = v;
      }
    __syncthreads();
    if (t < 64) {
      minv[rowbase + t] = fminf(mval[0][t], mval[1][t]);
      cnt[rowbase + t] = 0;
    }
    if (blockIdx.x == 0 && t == 0) *nflg = 0;
  }
}

// ---------- np-exact recheck of candidates (8 rows/block, 32 lanes/row) ----------
__global__ __launch_bounds__(256) void vq_recheck(const float* __restrict__ x,
                                                  const float* __restrict__ cb,
                                                  const float* __restrict__ se,
                                                  const int* __restrict__ cnt,
                                                  const int* __restrict__ cand,
                                                  float* __restrict__ outids,
                                                  int* __restrict__ flg,
                                                  int* __restrict__ nflg) {
#pragma clang fp contract(off)
  __shared__ float xr[8][256];
  __shared__ float sxs[8];
  const int t = threadIdx.x;
  const int r0 = blockIdx.x * 8;
  const int b = r0 >> 10, hw0 = r0 & 1023;
  {
    const float* px = x + ((size_t)b * CD + t) * HW + hw0;
    const float4 v0 = *(const float4*)(px);
    const float4 v1 = *(const float4*)(px + 4);
    xr[0][t] = v0.x; xr[1][t] = v0.y; xr[2][t] = v0.z; xr[3][t] = v0.w;
    xr[4][t] = v1.x; xr[5][t] = v1.y; xr[6][t] = v1.z; xr[7][t] = v1.w;
  }
  __syncthreads();
  if (t < 8) {   // np pairwise sx (verified order)
    float half[2];
#pragma unroll
    for (int h = 0; h < 2; ++h) {
      float racc[8];
#pragma unroll
      for (int j = 0; j < 8; ++j) { const float v = xr[t][h * 128 + j]; racc[j] = v * v; }
#pragma unroll
      for (int i = 1; i < 16; ++i)
#pragma unroll
        for (int j = 0; j < 8; ++j) {
          const float v = xr[t][h * 128 + 8 * i + j];
          const float v2 = v * v;
          racc[j] = racc[j] + v2;
        }
      half[h] = ((racc[0] + racc[1]) + (racc[2] + racc[3])) +
                ((racc[4] + racc[5]) + (racc[6] + racc[7]));
    }
    sxs[t] = half[0] + half[1];
  }
  __syncthreads();

  const int g = t >> 5, ln = t & 31;
  const int row = r0 + g;
  const int cn = cnt[row];
  float bv = FLT_MAX;
  int bi = 0x7FFFFFFF;
  if (cn > CAP) {
    if (ln == 0) { const int p = atomicAdd(nflg, 1); flg[p] = row; }
  } else {
    const float sx = sxs[g];
    const float* xrow = xr[g];
    for (int c = ln; c < cn; c += 32) {
      const int k = cand[(size_t)row * CAP + c];
      const float* ek = cb + (size_t)k * CD;
      float a0 = 0.f, a1 = 0.f, a2 = 0.f, a3 = 0.f;
      for (int B = 0; B < 16; ++B)
        for (int j = 3; j >= 0; --j) {
          const int c0 = 16 * B + 4 * j;
          float p0 = xrow[c0 + 0] * ek[c0 + 0]; a0 = a0 + p0;
          float p1 = xrow[c0 + 1] * ek[c0 + 1]; a1 = a1 + p1;
          float p2 = xrow[c0 + 2] * ek[c0 + 2]; a2 = a2 + p2;
          float p3 = xrow[c0 + 3] * ek[c0 + 3]; a3 = a3 + p3;
        }
      const float dot = (a0 + a1) + (a2 + a3);
      const float dist = (se[k] + sx) - 2.0f * dot;
      if (dist < bv || (dist == bv && k < bi)) { bv = dist; bi = k; }
    }
  }
#pragma unroll
  for (int off = 1; off < 32; off <<= 1) {
    const float ov = __shfl_xor(bv, off, 32);
    const int oi = __shfl_xor(bi, off, 32);
    if (ov < bv || (ov == bv && oi < bi)) { bv = ov; bi = oi; }
  }
  if (ln == 0 && cn <= CAP) outids[row] = (float)bi;
}

// ---------- full-row np-exact fallback for overflow rows ----------
__global__ __launch_bounds__(256) void vq_fallback(const float* __restrict__ x,
                                                   const float* __restrict__ cb,
                                                   const float* __restrict__ se,
                                                   const int* __restrict__ flg,
                                                   const int* __restrict__ nflg,
                                                   float* __restrict__ outids) {
#pragma clang fp contract(off)
  __shared__ float xr[256];
  __shared__ float sxv;
  __shared__ float rv[256];
  __shared__ int ri[256];
  const int t = threadIdx.x;
  const int nf = *nflg;
  for (int fi = blockIdx.x; fi < nf; fi += gridDim.x) {
    const int row = flg[fi];
    const int b = row >> 10, hw = row & 1023;
    __syncthreads();
    xr[t] = x[((size_t)b * CD + t) * HW + hw];
    __syncthreads();
    if (t == 0) {
      float half[2];
      for (int h = 0; h < 2; ++h) {
        float racc[8];
        for (int j = 0; j < 8; ++j) { const float v = xr[h * 128 + j]; racc[j] = v * v; }
        for (int i = 1; i < 16; ++i)
          for (int j = 0; j < 8; ++j) {
            const float v = xr[h * 128 + 8 * i + j];
            const float v2 = v * v;
            racc[j] = racc[j] + v2;
          }
        half[h] = ((racc[0] + racc[1]) + (racc[2] + racc[3])) +
                  ((racc[4] + racc[5]) + (racc[6] + racc[7]));
      }
      sxv = half[0] + half[1];
    }
    __syncthreads();
    float bv = FLT_MAX;
    int bi = 0x7FFFFFFF;
    for (int j = 0; j < 16; ++j) {
      const int k = j * 256 + t;
      const float* ek = cb + (size_t)k * CD;
      float a0 = 0.f, a1 = 0.f, a2 = 0.f, a3 = 0.f;
      for (int B = 0; B < 16; ++B)
        for (int jj = 3; jj >= 0; --jj) {
          const int c0 = 16 * B + 4 * jj;
          float p0 = xr[c0 + 0] * ek[c0 + 0]; a0 = a0 + p0;
          float p1 = xr[c0 + 1] * ek[c0 + 1]; a1 = a1 + p1;
          float p2 = xr[c0 + 2] * ek[c0 + 2]; a2 = a2 + p2;
          float p3 = xr[c0 + 3] * ek[c0 + 3]; a3 = a3 + p3;
        }
      const float dot = (a0 + a1) + (a2 + a3);
      const float dist = (se[k] + sxv) - 2.0f * dot;
      if (dist < bv || (dist == bv && k < bi)) { bv = dist; bi = k; }
    }
    rv[t] = bv; ri[t] = bi;
    __syncthreads();
    for (int off = 128; off > 0; off >>= 1) {
      if (t < off) {
        if (rv[t + off] < rv[t] || (rv[t + off] == rv[t] && ri[t + off] < ri[t])) {
          rv[t] = rv[t + off]; ri[t] = ri[t + off];
        }
      }
      __syncthreads();
    }
    if (t == 0) outids[row] = (float)ri[0];
  }
}

// ---------- emb gather [verified] ----------
__global__ __launch_bounds__(256) void vq_emb_out(const float* __restrict__ outids,
                                                  const float* __restrict__ cb,
                                                  float* __restrict__ out) {
  const int bx = blockIdx.x;
  const int b = bx >> 10;
  const int rem = bx & 1023;
  const int c = rem >> 2;
  const int q = rem & 3;
  const int hw = q * 256 + threadIdx.x;
  const int id = (int)outids[b * HW + hw];
  out[((size_t)(b * CD + c)) * HW + hw] = cb[(size_t)id * CD + c];
}

extern "C" void kernel_launch(void* const* d_in, const int* in_sizes, int n_in,
                              void* d_out, int out_size, void* d_ws, size_t ws_size,
                              hipStream_t stream) {
  const float* x  = (const float*)d_in[0];   // (32,256,32,32) f32
  const float* cb = (const float*)d_in[1];   // (4096,256) f32
  float* out = (float*)d_out;                // [0..32767]=ids, [32768..]=emb

  float* se = (float*)d_ws;                  // 16 KB

  // scratch inside the emb region (8,388,608 floats), overwritten last by gather
  float* sc = out + NRW;
  unsigned short* xh = (unsigned short*)sc;              // 4,194,304 floats (16.8 MB)
  unsigned short* eh = (unsigned short*)(sc + 4194304);  //   524,288 floats (2.1 MB)
  float* minv = sc + 4718592;                            //    32,768
  int*   cnt  = (int*)(sc + 4751360);                    //    32,768
  int*   flg  = (int*)(sc + 4784128);                    //    32,768
  int*   nflg = (int*)(sc + 4816896);                    //         1
  int*   cand = (int*)(sc + 4816960);                    // 2,097,152 (ends 6,914,112 < 8,388,608)

  vq_se<<<KC / 32, 256, 0, stream>>>(cb, se);
  vq_cvt_x<<<512, 256, 0, stream>>>(x, xh);
  vq_cvt_e<<<1024, 256, 0, stream>>>(cb, eh);
  vq_gemm<1><<<512, 256, 0, stream>>>(xh, eh, se, minv, cnt, nflg, cand);
  vq_gemm<2><<<512, 256, 0, stream>>>(xh, eh, se, minv, cnt, nflg, cand);
  vq_recheck<<<NRW / 8, 256, 0, stream>>>(x, cb, se, cnt, cand, out, flg, nflg);
  vq_fallback<<<512, 256, 0, stream>>>(x, cb, se, flg, nflg, out);
  vq_emb_out<<<32768, 256, 0, stream>>>(out, cb, out + NRW);
}